// Round 1
// baseline (589.915 us; speedup 1.0000x reference)
//
#include <hip/hip_runtime.h>
#include <math.h>

// FractalOpponent: batch-1 recursive LSTM/MoE tree on MI355X.
// Strategy: fixed sequence of predicated kernels (device-side control flow via
// `steps` flags in workspace); split-K atomic GEMVs, everything on `stream`.

#define H 2048

__device__ __forceinline__ bool pred_ok(const int* fA, int loA, int hiA,
                                        const int* fB, int loB, int hiB) {
  if (fA) { int v = *fA; if (v < loA || v > hiA) return false; }
  if (fB) { int v = *fB; if (v < loB || v > hiB) return false; }
  return true;
}

// y[j] += sum_i x[i] * W[i,j]; x is concat(xA, xB) split at splitPt.
// Block: 256 thr = 64 lanes (j, float4) x 4 k-subsplits. Grid: (N/256)*KS.
// expertMode: W is [4][H][H], output j = e*H + k.
__global__ void k_gemv(const float* __restrict__ xA, const float* __restrict__ xB,
                       int splitPt,
                       const float* __restrict__ W, float* __restrict__ y,
                       int K, int N, int KS, int expertMode,
                       const int* fA, int loA, int hiA,
                       const int* fB, int loB, int hiB)
{
  if (!pred_ok(fA, loA, hiA, fB, loB, hiB)) return;
  const int tid  = threadIdx.x;
  const int lane = tid & 63;
  const int tsub = tid >> 6;
  const int groups = N >> 8;
  const int g = blockIdx.x % groups;
  const int s = blockIdx.x / groups;
  const int j = (g << 8) + (lane << 2);
  const int chunk = K / KS;
  const int len = chunk >> 2;
  const int i0 = s * chunk + tsub * len;

  const float* Wp;
  long long rowStride;
  if (expertMode) {
    const long long e = j >> 11;
    const int k = j & (H - 1);
    Wp = W + (e << 22) + (long long)i0 * H + k;
    rowStride = H;
  } else {
    Wp = W + (long long)i0 * N + j;
    rowStride = N;
  }
  float ax = 0.f, ay = 0.f, az = 0.f, aw = 0.f;
  for (int t = 0; t < len; ++t) {
    const int i = i0 + t;
    const float xi = (i < splitPt) ? xA[i] : xB[i - splitPt];
    const float4 w = *reinterpret_cast<const float4*>(Wp);
    ax = fmaf(xi, w.x, ax); ay = fmaf(xi, w.y, ay);
    az = fmaf(xi, w.z, az); aw = fmaf(xi, w.w, aw);
    Wp += rowStride;
  }
  __shared__ float4 red[256];
  red[tid] = make_float4(ax, ay, az, aw);
  __syncthreads();
  if (tsub == 0) {
    float4 a = red[tid], b = red[tid + 64], c = red[tid + 128], d = red[tid + 192];
    atomicAdd(&y[j + 0], a.x + b.x + c.x + d.x);
    atomicAdd(&y[j + 1], a.y + b.y + c.y + d.y);
    atomicAdd(&y[j + 2], a.z + b.z + c.z + d.z);
    atomicAdd(&y[j + 3], a.w + b.w + c.w + d.w);
  }
}

// Per-node init: t_hv=0, attn=0, gates=b_lstm, eo=expert_b. 20480 elems, grid 80.
__global__ void k_node_init(float* t_hv, float* attn, float* gates, const float* b_lstm,
                            float* eo, const float* expert_b,
                            const int* fA, int loA, int hiA,
                            const int* fB, int loB, int hiB)
{
  if (!pred_ok(fA, loA, hiA, fB, loB, hiB)) return;
  int i = blockIdx.x * 256 + threadIdx.x;
  if (i < 2048) t_hv[i] = 0.f;
  else if (i < 4096) attn[i - 2048] = 0.f;
  else if (i < 12288) gates[i - 4096] = b_lstm[i - 4096];
  else if (i < 20480) eo[i - 12288] = expert_b[i - 12288];
}

__global__ void k_lstm(const float* __restrict__ gates, const float* __restrict__ c_in,
                       float* __restrict__ h_out, float* __restrict__ c_out,
                       const int* fA, int loA, int hiA,
                       const int* fB, int loB, int hiB)
{
  if (!pred_ok(fA, loA, hiA, fB, loB, hiB)) return;
  int j = blockIdx.x * 256 + threadIdx.x;
  if (j >= H) return;
  float gi = gates[j], gf = gates[H + j], gg = gates[2 * H + j], go = gates[3 * H + j];
  float si = 1.f / (1.f + expf(-gi));
  float sf = 1.f / (1.f + expf(-gf));
  float so = 1.f / (1.f + expf(-go));
  float c2 = sf * c_in[j] + si * tanhf(gg);
  float h2 = so * tanhf(c2);
  c_out[j] = c2;
  h_out[j] = h2;
}

// Single block: router logits -> softmax p -> hp = sum_e p_e*eo_e -> depth logits
// -> steps = min(argmax, maxSteps). Writes hp_out; optionally *stepsOut.
__global__ void k_combine(const float* __restrict__ hs,
                          const float* __restrict__ router_w, const float* __restrict__ router_b,
                          const float* __restrict__ eo, float* __restrict__ hp_out,
                          const float* __restrict__ dr_w, const float* __restrict__ dr_b,
                          int maxSteps, int* stepsOut,
                          const int* fA, int loA, int hiA,
                          const int* fB, int loB, int hiB)
{
  if (!pred_ok(fA, loA, hiA, fB, loB, hiB)) return;
  __shared__ float rl[4];
  __shared__ float shp[H];
  const int tid = threadIdx.x, lane = tid & 63, wv = tid >> 6;
  float a = 0.f;
  for (int i = lane; i < H; i += 64) a += hs[i] * router_w[i * 4 + wv];
  for (int off = 32; off > 0; off >>= 1) a += __shfl_down(a, off);
  if (lane == 0) rl[wv] = a + router_b[wv];
  __syncthreads();
  const float m = fmaxf(fmaxf(rl[0], rl[1]), fmaxf(rl[2], rl[3]));
  const float e0 = expf(rl[0] - m), e1 = expf(rl[1] - m), e2 = expf(rl[2] - m), e3 = expf(rl[3] - m);
  const float inv = 1.f / (e0 + e1 + e2 + e3);
  const float p0 = e0 * inv, p1 = e1 * inv, p2 = e2 * inv, p3 = e3 * inv;
  for (int k = tid; k < H; k += 256) {
    float v = p0 * eo[k] + p1 * eo[H + k] + p2 * eo[2 * H + k] + p3 * eo[3 * H + k];
    hp_out[k] = v;
    shp[k] = v;
  }
  if (stepsOut) {
    __syncthreads();
    float d0 = 0.f, d1 = 0.f, d2 = 0.f;
    for (int k = tid; k < H; k += 256) {
      float v = shp[k];
      d0 += v * dr_w[k * 3 + 0];
      d1 += v * dr_w[k * 3 + 1];
      d2 += v * dr_w[k * 3 + 2];
    }
    __shared__ float r0[256], r1[256], r2[256];
    r0[tid] = d0; r1[tid] = d1; r2[tid] = d2;
    __syncthreads();
    for (int off = 128; off > 0; off >>= 1) {
      if (tid < off) { r0[tid] += r0[tid + off]; r1[tid] += r1[tid + off]; r2[tid] += r2[tid + off]; }
      __syncthreads();
    }
    if (tid == 0) {
      float l0 = r0[0] + dr_b[0], l1 = r1[0] + dr_b[1], l2 = r2[0] + dr_b[2];
      int ch = 0; float bv = l0;
      if (l1 > bv) { bv = l1; ch = 1; }
      if (l2 > bv) { bv = l2; ch = 2; }
      *stepsOut = (ch < maxSteps) ? ch : maxSteps;
    }
  }
}

__global__ void k_copy3(const float* a, float* A, const float* b, float* B,
                        const float* c, float* C,
                        const int* fA, int loA, int hiA,
                        const int* fB, int loB, int hiB)
{
  if (!pred_ok(fA, loA, hiA, fB, loB, hiB)) return;
  int j = blockIdx.x * 256 + threadIdx.x;
  if (j >= H) return;
  A[j] = a[j]; B[j] = b[j]; C[j] = c[j];
}

// Internal-node finalize prep: h_next, ramanujan agg (2 states), anchor/gacc init,
// and ret_f/ret_c pass-through from child.
__global__ void k_finprep(const float* hp, const float* rh_child, float damping,
                          float* hn, float* agg, float* anchor, const float* ram_b,
                          float* gacc, const float* ag_b,
                          float* rf, const float* rf_child, float* rc, const float* rc_child,
                          const int* fA, int loA, int hiA,
                          const int* fB, int loB, int hiB)
{
  if (!pred_ok(fA, loA, hiA, fB, loB, hiB)) return;
  int j = blockIdx.x * 256 + threadIdx.x;
  if (j >= H) return;
  float h0 = hp[j], d = rh_child[j];
  float hnj = h0 + damping * (d - h0);
  hn[j] = hnj;
  agg[j] = h0 - 0.5f * hnj;
  anchor[j] = ram_b[j];
  gacc[j] = ag_b[j];
  rf[j] = rf_child[j];
  rc[j] = rc_child[j];
}

__global__ void k_fingate(const float* gacc, const float* anchor, const float* hcur, float* rh,
                          const int* fA, int loA, int hiA,
                          const int* fB, int loB, int hiB)
{
  if (!pred_ok(fA, loA, hiA, fB, loB, hiB)) return;
  int j = blockIdx.x * 256 + threadIdx.x;
  if (j >= H) return;
  float g = 1.f / (1.f + expf(-gacc[j]));
  rh[j] = g * anchor[j] + (1.f - g) * hcur[j];
}

__global__ void k_lerp(const float* a, const float* b, float damping, float* outp,
                       const int* fA, int loA, int hiA,
                       const int* fB, int loB, int hiB)
{
  if (!pred_ok(fA, loA, hiA, fB, loB, hiB)) return;
  int j = blockIdx.x * 256 + threadIdx.x;
  if (j >= H) return;
  float av = a[j];
  outp[j] = av + damping * (b[j] - av);
}

// Depth-0 finalize prep (selects based on s0 == 1 or 2).
__global__ void k_fin0prep(const int* s0p, const float* hp0, const float* hnA, const float* hnB,
                           float* agg, float* hc0, float* anchor, const float* ram_b,
                           float* gacc, const float* ag_b,
                           float* outF, const float* rf1, const float* rf3,
                           float* outC, const float* rc1, const float* rc3)
{
  int s0v = *s0p;
  if (s0v < 1) return;
  int j = blockIdx.x * 256 + threadIdx.x;
  if (j >= H) return;
  float ag = hp0[j] - 0.5f * hnA[j];
  float hc;
  if (s0v >= 2) {
    ag += (1.f / 3.f) * hnB[j];
    hc = hnB[j];
    outF[j] = rf3[j];
    outC[j] = rc3[j];
  } else {
    hc = hnA[j];
    outF[j] = rf1[j];
    outC[j] = rc1[j];
  }
  agg[j] = ag;
  hc0[j] = hc;
  anchor[j] = ram_b[j];
  gacc[j] = ag_b[j];
}

extern "C" void kernel_launch(void* const* d_in, const int* in_sizes, int n_in,
                              void* d_out, int out_size, void* d_ws, size_t ws_size,
                              hipStream_t stream) {
  const float* x        = (const float*)d_in[0];
  const float* h_in0    = (const float*)d_in[1];
  const float* c_in0    = (const float*)d_in[2];
  const float* Wv       = (const float*)d_in[5];
  const float* Wo       = (const float*)d_in[6];
  const float* Wih      = (const float*)d_in[7];
  const float* Whh      = (const float*)d_in[8];
  const float* b_lstm   = (const float*)d_in[9];
  const float* router_w = (const float*)d_in[10];
  const float* router_b = (const float*)d_in[11];
  const float* expert_w = (const float*)d_in[12];
  const float* expert_b = (const float*)d_in[13];
  const float* dr_w     = (const float*)d_in[14];
  const float* dr_b     = (const float*)d_in[15];
  const float* ram_w    = (const float*)d_in[16];
  const float* ram_b    = (const float*)d_in[17];
  const float* ag_w     = (const float*)d_in[18];
  const float* ag_b     = (const float*)d_in[19];
  float* out = (float*)d_out;

  // ---- workspace layout (~385 KB) ----
  int* s0  = (int*)d_ws;
  int* s1A = s0 + 1;
  int* s1B = s0 + 2;
  float* F = (float*)((char*)d_ws + 256);
  float* t_hv  = F;
  float* attn  = F + 2048;
  float* gates = F + 4096;   // 8192
  float* eo    = F + 12288;  // 8192
  auto NB = [&](int n) { return F + 20480 + (long long)n * 12288; };
  float* so0 = NB(0); float* cs0 = so0 + 2048; float* hp0 = so0 + 4096;
  float* so1 = NB(1); float* cs1 = so1 + 2048; float* hp1 = so1 + 4096;
  float* rf1 = so1 + 6144; float* rh1 = so1 + 8192; float* rc1 = so1 + 10240;
  float* rf2 = NB(2) + 6144; float* rh2 = NB(2) + 8192; float* rc2 = NB(2) + 10240;
  float* so3 = NB(3); float* cs3 = so3 + 2048; float* hp3 = so3 + 4096;
  float* rf3 = so3 + 6144; float* rh3 = so3 + 8192; float* rc3 = so3 + 10240;
  float* rf4 = NB(4) + 6144; float* rh4 = NB(4) + 8192; float* rc4 = NB(4) + 10240;
  float* hnA0   = F + 81920;
  float* hnB0   = F + 83968;
  float* hn1    = F + 86016;  // shared scratch for depth-1 finalize (sequential use)
  float* agg    = F + 88064;
  float* anchor = F + 90112;
  float* gacc   = F + 92160;
  float* hc0b   = F + 94208;

  const int* NO = nullptr;

  auto gemv = [&](const float* xA, const float* xB, int splitPt,
                  const float* W, float* y, int K, int N, int KS, int em,
                  const int* fA, int loA, int hiA, const int* fB, int loB, int hiB) {
    k_gemv<<<dim3((N >> 8) * KS), dim3(256), 0, stream>>>(
        xA, xB, splitPt, W, y, K, N, KS, em, fA, loA, hiA, fB, loB, hiB);
  };

  // One tree node: cell_step + path_gate + (optional) depth decision.
  auto node = [&](const float* hv, const float* cv, float* soB, float* csB, float* hpB,
                  int maxSteps, int* stepsOut,
                  const int* fA, int loA, int hiA, const int* fB, int loB, int hiB) {
    k_node_init<<<80, 256, 0, stream>>>(t_hv, attn, gates, b_lstm, eo, expert_b,
                                        fA, loA, hiA, fB, loB, hiB);
    gemv(hv, hv, H, Wv, t_hv, H, H, 64, 0, fA, loA, hiA, fB, loB, hiB);
    gemv(x, x, H, Wih, gates, H, 4 * H, 16, 0, fA, loA, hiA, fB, loB, hiB);
    gemv(t_hv, t_hv, H, Wo, attn, H, H, 64, 0, fA, loA, hiA, fB, loB, hiB);
    gemv(attn, attn, H, Whh, gates, H, 4 * H, 16, 0, fA, loA, hiA, fB, loB, hiB);
    k_lstm<<<8, 256, 0, stream>>>(gates, cv, soB, csB, fA, loA, hiA, fB, loB, hiB);
    gemv(soB, soB, H, expert_w, eo, H, 4 * H, 16, 1, fA, loA, hiA, fB, loB, hiB);
    k_combine<<<1, 256, 0, stream>>>(soB, router_w, router_b, eo, hpB, dr_w, dr_b,
                                     maxSteps, stepsOut, fA, loA, hiA, fB, loB, hiB);
  };

  // ---- N0 (depth 0) ----
  node(h_in0, c_in0, so0, cs0, hp0, 2, s0, NO, 0, 0, NO, 0, 0);
  // ---- N1 (depth 1), pred s0>=1 ----
  node(hp0, cs0, so1, cs1, hp1, 1, s1A, s0, 1, 99, NO, 0, 0);
  // ---- N2 (depth 2 leaf), pred s0>=1 && s1A>=1; so/cs/hp -> ret slots directly
  node(hp1, cs1, rf2, rc2, rh2, 0, nullptr, s0, 1, 99, s1A, 1, 99);
  // ---- N1 finalize ----
  k_copy3<<<8, 256, 0, stream>>>(so1, rf1, hp1, rh1, cs1, rc1, s0, 1, 99, s1A, 0, 0);
  k_finprep<<<8, 256, 0, stream>>>(hp1, rh2, 0.25f, hn1, agg, anchor, ram_b, gacc, ag_b,
                                   rf1, rf2, rc1, rc2, s0, 1, 99, s1A, 1, 99);
  gemv(agg, hp1, H, ram_w, anchor, 2 * H, H, 64, 0, s0, 1, 99, s1A, 1, 99);
  gemv(hn1, anchor, H, ag_w, gacc, 2 * H, H, 64, 0, s0, 1, 99, s1A, 1, 99);
  k_fingate<<<8, 256, 0, stream>>>(gacc, anchor, hn1, rh1, s0, 1, 99, s1A, 1, 99);
  // ---- glue: h after first d0 child (damping = 1) ----
  k_lerp<<<8, 256, 0, stream>>>(hp0, rh1, 1.0f, hnA0, s0, 1, 99, NO, 0, 0);
  // ---- N3 (depth 1), pred s0>=2 ----
  node(hnA0, rc1, so3, cs3, hp3, 1, s1B, s0, 2, 99, NO, 0, 0);
  // ---- N4 (depth 2 leaf), pred s0>=2 && s1B>=1 ----
  node(hp3, cs3, rf4, rc4, rh4, 0, nullptr, s0, 2, 99, s1B, 1, 99);
  // ---- N3 finalize ----
  k_copy3<<<8, 256, 0, stream>>>(so3, rf3, hp3, rh3, cs3, rc3, s0, 2, 99, s1B, 0, 0);
  k_finprep<<<8, 256, 0, stream>>>(hp3, rh4, 0.25f, hn1, agg, anchor, ram_b, gacc, ag_b,
                                   rf3, rf4, rc3, rc4, s0, 2, 99, s1B, 1, 99);
  gemv(agg, hp3, H, ram_w, anchor, 2 * H, H, 64, 0, s0, 2, 99, s1B, 1, 99);
  gemv(hn1, anchor, H, ag_w, gacc, 2 * H, H, 64, 0, s0, 2, 99, s1B, 1, 99);
  k_fingate<<<8, 256, 0, stream>>>(gacc, anchor, hn1, rh3, s0, 2, 99, s1B, 1, 99);
  // ---- glue: h after second d0 child ----
  k_lerp<<<8, 256, 0, stream>>>(hnA0, rh3, 1.0f, hnB0, s0, 2, 99, NO, 0, 0);
  // ---- N0 finalize ----
  // s0==0 leaf path writes d_out directly
  k_copy3<<<8, 256, 0, stream>>>(so0, out, hp0, out + H, cs0, out + 2 * H, s0, 0, 0, NO, 0, 0);
  k_fin0prep<<<8, 256, 0, stream>>>(s0, hp0, hnA0, hnB0, agg, hc0b, anchor, ram_b, gacc, ag_b,
                                    out, rf1, rf3, out + 2 * H, rc1, rc3);
  gemv(agg, hp0, H, ram_w, anchor, 2 * H, H, 64, 0, s0, 1, 99, NO, 0, 0);
  gemv(hc0b, anchor, H, ag_w, gacc, 2 * H, H, 64, 0, s0, 1, 99, NO, 0, 0);
  k_fingate<<<8, 256, 0, stream>>>(gacc, anchor, hc0b, out + H, s0, 1, 99, NO, 0, 0);
}